// Round 4
// baseline (1974.222 us; speedup 1.0000x reference)
//
#include <hip/hip_runtime.h>
#include <math.h>

#define S_  5
#define B_  2
#define C_  128
#define N_  576
#define SB  10
#define NPAIR 40
#define C2  256

typedef short v8s __attribute__((ext_vector_type(8)));
typedef float v4f __attribute__((ext_vector_type(4)));

__device__ __forceinline__ unsigned short f2bf(float f) {
    union { float f; unsigned u; } v; v.f = f;
    unsigned r = (v.u + 0x7FFF + ((v.u >> 16) & 1)) >> 16;
    return (unsigned short)r;
}
__device__ __forceinline__ float bf2f(unsigned short h) {
    union { unsigned u; float f; } v; v.u = ((unsigned)h) << 16;
    return v.f;
}

// ------------------------------------------------------------------ weight packs
__global__ void pack3_kernel(const float* __restrict__ wf, const float* __restrict__ wh,
                             const float* __restrict__ wl, unsigned short* __restrict__ Wp3)
{
    int idx = blockIdx.x * 256 + threadIdx.x;
    if (idx >= 384 * 1152) return;
    int co = idx / 1152, k = idx % 1152;
    int tap = k >> 7, ci = k & 127;
    const float* w = (co < 128) ? wf : (co < 256) ? wh : wl;
    int c = co & 127;
    Wp3[idx] = f2bf(w[((size_t)c * 128 + ci) * 9 + tap]);
}
__global__ void pack5_kernel(const float* __restrict__ w, unsigned short* __restrict__ Wp, int M)
{
    int idx = blockIdx.x * 256 + threadIdx.x;
    if (idx >= M * 6400) return;
    int co = idx / 6400, k = idx % 6400;
    int tap = k >> 8, ci = k & 255;
    Wp[idx] = f2bf(w[((size_t)co * 256 + ci) * 25 + tap]);
}
__global__ void packWc_kernel(const float* __restrict__ w, unsigned short* __restrict__ o)
{
    int idx = blockIdx.x * 256 + threadIdx.x;
    if (idx < 128 * 128) o[idx] = f2bf(w[idx]);
}

// ---------------------------------------------- transpose-cast: [c][px] f32 -> [px][c] bf16
// zrp != null: multiply by r = sigmoid(zrp0[128+c] + zrp1[128+c] + zrb[128+c]) (builds r*h)
// dst2 != null: also write bf16 [c][px]
__global__ __launch_bounds__(256) void tc_kernel(
    const float* __restrict__ src, const float* __restrict__ zrp,
    const float* __restrict__ zrb,
    unsigned short* __restrict__ dst, unsigned short* __restrict__ dst2)
{
    const size_t PLANE = (size_t)SB * C2 * N_;
    __shared__ float tile[128][65];
    int img = blockIdx.y, px0 = blockIdx.x * 64, t = threadIdx.x;
    #pragma unroll
    for (int i = 0; i < 32; ++i) {
        int e = i * 256 + t; int ci = e >> 6; int px = e & 63;
        float v = src[((size_t)img * 128 + ci) * 576 + px0 + px];
        if (zrp) {
            size_t zi = ((size_t)img * C2 + 128 + ci) * 576 + px0 + px;
            float a = zrp[zi] + zrp[PLANE + zi] + zrb[128 + ci];
            v *= 1.f / (1.f + __expf(-a));
        }
        tile[ci][px] = v;
        if (dst2) dst2[((size_t)img * 128 + ci) * 576 + px0 + px] = f2bf(v);
    }
    __syncthreads();
    #pragma unroll
    for (int i = 0; i < 32; ++i) {
        int e = i * 256 + t; int px = e >> 7; int ci = e & 127;
        dst[((size_t)img * 576 + px0 + px) * 128 + ci] = f2bf(tile[ci][px]);
    }
}

// ------------------------------------------------------ MFMA implicit-GEMM conv v2
// block tile: 128co x 64px, 4 waves (wave = 64co x 32px)
// K: 4 ci-chunks of 32 (per K-half when SPLITK=2); tap inner, fully unrolled
// A (weights) direct-global with depth-3 register prefetch; B window dbuf LDS
// MODE 0: conv3x3 -> bf16 ftT/htT/lt outputs (+bias)   MODE 1: f32 partials to po
template<int TAPS, int R, int SPLITK, int MODE>
__global__ __launch_bounds__(256, 2) void conv_mfma(
    const unsigned short* __restrict__ srcA, const unsigned short* __restrict__ srcB,
    const unsigned short* __restrict__ Wp, int COUT,
    const float* __restrict__ b0, const float* __restrict__ b1, const float* __restrict__ b2,
    float* __restrict__ po,
    unsigned short* __restrict__ t0, unsigned short* __restrict__ t1,
    unsigned short* __restrict__ t2)
{
    constexpr int KD   = 2 * R + 1;
    constexpr int WR   = 4 + 2 * R;
    constexpr int WC   = 24 + 2 * R;
    constexpr int NPOS = WR * WC;
    constexpr int CIN  = (SPLITK == 2) ? 256 : 128;
    constexpr int KTOT = TAPS * CIN;
    constexpr int NCH  = 4;
    constexpr int LOADS = (NPOS * 4 + 255) / 256;
    __shared__ __align__(16) unsigned short Xs[2][NPOS * 32];

    int f   = blockIdx.x;
    int kk  = (SPLITK == 2) ? (f & 1) : 0;
    int cgb = (SPLITK == 2) ? (f >> 1) : f;
    int pxb = blockIdx.y;
    int img = blockIdx.z;
    int t = threadIdx.x;
    int wave = t >> 6, lane = t & 63;
    int quad = lane >> 4, l15 = lane & 15;
    int cgw = wave & 1, pgw = wave >> 1;
    int px0w = pxb * 64 + pgw * 32;
    int r0 = (pxb * 64) / 24;

    const unsigned short* src = (SPLITK == 2 && kk == 1) ? srcB : srcA;
    const unsigned short* srcI = src + (size_t)img * 576 * 128;

    int posBase[2], pxs[2];
    #pragma unroll
    for (int s = 0; s < 2; ++s) {
        int px = px0w + s * 16 + l15;
        pxs[s] = px;
        int pr = px / 24, pc = px % 24;
        posBase[s] = (pr - r0 + R) * WC + pc + R;
    }

    const unsigned short* wRow = Wp + (size_t)(cgb * 128 + cgw * 64 + l15) * KTOT
                                 + (SPLITK == 2 ? kk * 128 : 0) + quad * 8;

    v8s abuf[4][4];
    v8s svals[LOADS];
    v4f acc[4][2];
    #pragma unroll
    for (int c = 0; c < 4; ++c)
        #pragma unroll
        for (int s = 0; s < 2; ++s)
            #pragma unroll
            for (int r = 0; r < 4; ++r) acc[c][s][r] = 0.f;

    // ---- staging helpers (issue loads early, write late)
    auto issueLoads = [&](int ch) {
        #pragma unroll
        for (int i = 0; i < LOADS; ++i) {
            int idx = t + i * 256;
            v8s v;
            #pragma unroll
            for (int j = 0; j < 8; ++j) v[j] = 0;
            if (idx < NPOS * 4) {
                int pos = idx >> 2, gr = idx & 3;
                int wr = pos / WC, wc = pos % WC;
                int grow = r0 - R + wr, gcol = wc - R;
                if (grow >= 0 && grow < 24 && gcol >= 0 && gcol < 24)
                    v = *(const v8s*)(srcI + (size_t)(grow * 24 + gcol) * 128 + ch * 32 + gr * 8);
            }
            svals[i] = v;
        }
    };
    auto writeStage = [&](int buf) {
        #pragma unroll
        for (int i = 0; i < LOADS; ++i) {
            int idx = t + i * 256;
            if (idx < NPOS * 4) {
                int pos = idx >> 2, gr = idx & 3;
                *(v8s*)&Xs[buf][pos * 32 + ((gr ^ ((pos >> 1) & 3)) << 3)] = svals[i];
            }
        }
    };
    auto loadA = [&](int pch, int ptap, int slot) {
        const unsigned short* p = wRow + pch * 32 + ptap * CIN;
        #pragma unroll
        for (int c = 0; c < 4; ++c)
            abuf[slot][c] = *(const v8s*)(p + (size_t)c * 16 * KTOT);
    };

    issueLoads(0);
    loadA(0, 0, 0);
    if (TAPS > 1) loadA(0, 1, 1); else loadA(1, 0, 1);
    if (TAPS > 2) loadA(0, 2, 2); else loadA(1, 2 - TAPS, 2);
    writeStage(0);
    __syncthreads();

    #pragma unroll
    for (int gk = 0; gk < NCH * TAPS; ++gk) {
        const int ch = gk / TAPS;
        const int tap = gk % TAPS;
        if (tap == 0) {
            if (ch > 0) {
                writeStage(ch & 1);
                __syncthreads();
            }
            if (ch < NCH - 1) issueLoads(ch + 1);
        }
        const int pgk = gk + 3;
        if (pgk < NCH * TAPS)
            loadA(pgk / TAPS, pgk % TAPS, pgk & 3);

        const int dy = tap / KD - R, dx = tap % KD - R;
        const int doff = dy * WC + dx;
        v8s bfr[2];
        #pragma unroll
        for (int s = 0; s < 2; ++s) {
            int pos = posBase[s] + doff;
            bfr[s] = *(const v8s*)&Xs[ch & 1][pos * 32 + ((quad ^ ((pos >> 1) & 3)) << 3)];
        }
        #pragma unroll
        for (int c = 0; c < 4; ++c)
            #pragma unroll
            for (int s = 0; s < 2; ++s)
                acc[c][s] = __builtin_amdgcn_mfma_f32_16x16x32_bf16(abuf[gk & 3][c], bfr[s], acc[c][s], 0, 0, 0);
    }

    if (MODE == 1) {
        float* out = po + (size_t)kk * ((size_t)SB * COUT * 576)
                   + ((size_t)img * COUT + cgb * 128) * 576;
        #pragma unroll
        for (int c = 0; c < 4; ++c)
            #pragma unroll
            for (int s = 0; s < 2; ++s)
                #pragma unroll
                for (int r = 0; r < 4; ++r) {
                    int col = cgw * 64 + c * 16 + quad * 4 + r;
                    out[(size_t)col * 576 + pxs[s]] = acc[c][s][r];
                }
    } else {
        const float* bp = (cgb == 0) ? b0 : (cgb == 1) ? b1 : b2;
        #pragma unroll
        for (int c = 0; c < 4; ++c)
            #pragma unroll
            for (int s = 0; s < 2; ++s)
                #pragma unroll
                for (int r = 0; r < 4; ++r) {
                    int col = cgw * 64 + c * 16 + quad * 4 + r;
                    float v = acc[c][s][r] + bp[col];
                    if (cgb == 0)      t0[((size_t)img * 576 + pxs[s]) * 128 + col] = f2bf(v);
                    else if (cgb == 1) t1[((size_t)img * 576 + pxs[s]) * 128 + col] = f2bf(v);
                    else               t2[((size_t)img * 128 + col) * 576 + pxs[s]] = f2bf(v);
                }
    }
}

// ---------------------------------------------------------------- yt (MFMA)
__global__ __launch_bounds__(256) void yt_mfma(
    const unsigned short* __restrict__ hT, const unsigned short* __restrict__ Wcb,
    unsigned short* __restrict__ ytT)
{
    int t = threadIdx.x, wave = t >> 6, lane = t & 63;
    int q = lane >> 4, l15 = lane & 15;
    int n0 = blockIdx.x * 16, img = blockIdx.y;
    v4f acc[2];
    #pragma unroll
    for (int ct = 0; ct < 2; ++ct)
        #pragma unroll
        for (int r = 0; r < 4; ++r) acc[ct][r] = 0.f;
    #pragma unroll
    for (int kk = 0; kk < 4; ++kk) {
        v8s b = *(const v8s*)(hT + ((size_t)img * 576 + n0 + l15) * 128 + kk * 32 + q * 8);
        #pragma unroll
        for (int ct = 0; ct < 2; ++ct) {
            v8s a = *(const v8s*)(Wcb + (size_t)((wave * 2 + ct) * 16 + l15) * 128 + kk * 32 + q * 8);
            acc[ct] = __builtin_amdgcn_mfma_f32_16x16x32_bf16(a, b, acc[ct], 0, 0, 0);
        }
    }
    #pragma unroll
    for (int ct = 0; ct < 2; ++ct) {
        unsigned short* op = ytT + ((size_t)img * 576 + n0 + l15) * 128 + (wave * 2 + ct) * 16 + q * 4;
        #pragma unroll
        for (int r = 0; r < 4; ++r) op[r] = f2bf(acc[ct][r]);
    }
}

// ---------------------------------------------------- MFMA flash attention
template<int MODE>
__global__ __launch_bounds__(256) void attn_mfma(
    const unsigned short* __restrict__ QT, const unsigned short* __restrict__ KT,
    const unsigned short* __restrict__ Vc, float* __restrict__ Of,
    unsigned short* __restrict__ Oh, const float* __restrict__ addsrc,
    const float* __restrict__ alpha)
{
    __shared__ __align__(16) unsigned short P[16 * 576];
    __shared__ float redmx[4][16];
    __shared__ float redsm[4][16];
    int t = threadIdx.x;
    int wave = t >> 6, lane = t & 63;
    int q = lane >> 4, l15 = lane & 15;
    int n0 = blockIdx.x * 16;
    int p = blockIdx.y;
    int qimg, kimg;
    if (MODE == 0) { qimg = p; kimg = p; }
    else {
        int b = p & 1; int ij = p >> 1; int i = ij >> 2; int jj = ij & 3;
        int j = jj + (jj >= i ? 1 : 0);
        qimg = i * 2 + b; kimg = j * 2 + b;
    }
    const unsigned short* Qp = QT + ((size_t)qimg * 576 + n0) * 128;
    const unsigned short* Kp = KT + (size_t)kimg * 576 * 128;
    const unsigned short* Vp = Vc + (size_t)kimg * 128 * 576;

    v8s aq[4];
    #pragma unroll
    for (int kk = 0; kk < 4; ++kk)
        aq[kk] = *(const v8s*)(Qp + (size_t)l15 * 128 + kk * 32 + q * 8);

    v4f S[9];
    #pragma unroll
    for (int i = 0; i < 9; ++i)
        #pragma unroll
        for (int r = 0; r < 4; ++r) S[i][r] = 0.f;

    #pragma unroll
    for (int i = 0; i < 9; ++i) {
        int m0 = (wave * 9 + i) * 16;
        #pragma unroll
        for (int kk = 0; kk < 4; ++kk) {
            v8s b = *(const v8s*)(Kp + ((size_t)(m0 + l15)) * 128 + kk * 32 + q * 8);
            S[i] = __builtin_amdgcn_mfma_f32_16x16x32_bf16(aq[kk], b, S[i], 0, 0, 0);
        }
    }

    float mx[4];
    #pragma unroll
    for (int r = 0; r < 4; ++r) {
        float m = S[0][r];
        #pragma unroll
        for (int i = 1; i < 9; ++i) m = fmaxf(m, S[i][r]);
        #pragma unroll
        for (int off = 1; off < 16; off <<= 1) m = fmaxf(m, __shfl_xor(m, off));
        mx[r] = m;
    }
    if (l15 == 0) {
        #pragma unroll
        for (int r = 0; r < 4; ++r) redmx[wave][q * 4 + r] = mx[r];
    }
    __syncthreads();
    float sum[4];
    #pragma unroll
    for (int r = 0; r < 4; ++r) {
        float g = fmaxf(fmaxf(redmx[0][q * 4 + r], redmx[1][q * 4 + r]),
                        fmaxf(redmx[2][q * 4 + r], redmx[3][q * 4 + r]));
        float s = 0.f;
        #pragma unroll
        for (int i = 0; i < 9; ++i) { float e = __expf(S[i][r] - g); S[i][r] = e; s += e; }
        #pragma unroll
        for (int off = 1; off < 16; off <<= 1) s += __shfl_xor(s, off);
        sum[r] = s;
    }
    if (l15 == 0) {
        #pragma unroll
        for (int r = 0; r < 4; ++r) redsm[wave][q * 4 + r] = sum[r];
    }
    #pragma unroll
    for (int i = 0; i < 9; ++i) {
        int m = (wave * 9 + i) * 16 + l15;
        int cm = m >> 3, mo = m & 7;
        #pragma unroll
        for (int r = 0; r < 4; ++r) {
            int n = q * 4 + r;
            P[n * 576 + ((cm ^ (n & 7)) << 3) + mo] = f2bf(S[i][r]);
        }
    }
    __syncthreads();
    float inv[4];
    #pragma unroll
    for (int r = 0; r < 4; ++r)
        inv[r] = 1.f / (redsm[0][q * 4 + r] + redsm[1][q * 4 + r] +
                        redsm[2][q * 4 + r] + redsm[3][q * 4 + r]);

    v4f o[2];
    #pragma unroll
    for (int ct = 0; ct < 2; ++ct)
        #pragma unroll
        for (int r = 0; r < 4; ++r) o[ct][r] = 0.f;

    for (int s = 0; s < 18; ++s) {
        int cm = s * 4 + q;
        v8s a = *(const v8s*)&P[l15 * 576 + ((cm ^ (l15 & 7)) << 3)];
        #pragma unroll
        for (int ct = 0; ct < 2; ++ct) {
            int c = (wave * 2 + ct) * 16 + l15;
            v8s b = *(const v8s*)(Vp + (size_t)c * 576 + s * 32 + q * 8);
            o[ct] = __builtin_amdgcn_mfma_f32_16x16x32_bf16(a, b, o[ct], 0, 0, 0);
        }
    }

    #pragma unroll
    for (int ct = 0; ct < 2; ++ct) {
        int c = (wave * 2 + ct) * 16 + l15;
        size_t base = ((size_t)p * 128 + c) * 576 + n0 + q * 4;
        if (MODE == 0) {
            float al = alpha[0];
            #pragma unroll
            for (int r = 0; r < 4; ++r)
                Of[base + r] = al * o[ct][r] * inv[r] + addsrc[base + r];
        } else {
            #pragma unroll
            for (int r = 0; r < 4; ++r)
                Oh[base + r] = f2bf(o[ct][r] * inv[r]);
        }
    }
}

// ------------------------------------- window sums for analytic gate-conv mean
__global__ __launch_bounds__(64) void wsum_kernel(
    const unsigned short* __restrict__ mji, float* __restrict__ wsum)
{
    int pair = blockIdx.x, ci = blockIdx.y, lane = threadIdx.x;
    const unsigned short* p = mji + ((size_t)pair * C_ + ci) * N_;
    float T=0, R0=0, R23=0, Cl=0, Cr=0, c00=0, c0w=0, ch0=0, chw=0;
    for (int i = lane; i < N_; i += 64) {
        float v = bf2f(p[i]);
        int r = i / 24, cc = i % 24;
        T += v;
        if (r == 0)  R0  += v;
        if (r == 23) R23 += v;
        if (cc == 0)  Cl += v;
        if (cc == 23) Cr += v;
        if (i == 0)   c00 = v;
        if (i == 23)  c0w = v;
        if (i == 552) ch0 = v;
        if (i == 575) chw = v;
    }
    #pragma unroll
    for (int off = 32; off > 0; off >>= 1) {
        T  += __shfl_xor(T, off);  R0 += __shfl_xor(R0, off);  R23 += __shfl_xor(R23, off);
        Cl += __shfl_xor(Cl, off); Cr += __shfl_xor(Cr, off);
        c00 += __shfl_xor(c00, off); c0w += __shfl_xor(c0w, off);
        ch0 += __shfl_xor(ch0, off); chw += __shfl_xor(chw, off);
    }
    if (lane == 0) {
        float rowsub[3] = {R23, 0.f, R0};
        float colsub[3] = {Cr,  0.f, Cl};
        float corner[9] = {chw, 0.f, ch0,  0.f, 0.f, 0.f,  c0w, 0.f, c00};
        float* o = wsum + ((size_t)pair * C_ + ci) * 9;
        #pragma unroll
        for (int ky = 0; ky < 3; ++ky)
            #pragma unroll
            for (int kx = 0; kx < 3; ++kx)
                o[ky * 3 + kx] = T - rowsub[ky] - colsub[kx] + corner[ky * 3 + kx];
    }
}

__global__ __launch_bounds__(128) void g_kernel(
    const float* __restrict__ wsum, const float* __restrict__ Wg,
    const float* __restrict__ Wgb, float* __restrict__ g)
{
    __shared__ float sw[C_ * 9];
    int pair = blockIdx.x; int co = threadIdx.x;
    for (int i = co; i < C_ * 9; i += 128) sw[i] = wsum[(size_t)pair * C_ * 9 + i];
    __syncthreads();
    const float* w = Wg + (size_t)co * C_ * 9;
    float acc = 0.f;
    for (int i = 0; i < C_ * 9; ++i) acc += w[i] * sw[i];
    float m = acc * (1.f / 576.f) + Wgb[co];
    g[pair * C_ + co] = 1.f / (1.f + __expf(-m));
}

__global__ void msg_kernel(
    const float* __restrict__ eii, const unsigned short* __restrict__ mji,
    const float* __restrict__ g, const float* __restrict__ bn_gamma,
    const float* __restrict__ bn_beta, const float* __restrict__ intra_w,
    const float* __restrict__ inter_w, float* __restrict__ msg)
{
    int e = blockIdx.x * blockDim.x + threadIdx.x;
    if (e >= SB * C_ * N_) return;
    int n = e % N_;
    int c = (e / N_) % C_;
    int img = e / (N_ * C_);
    int s = img >> 1, b = img & 1;
    float scale = bn_gamma[c] * rsqrtf(1.f + 1e-5f);
    float acc = 0.f;
    #pragma unroll
    for (int jj = 0; jj < 4; ++jj) {
        int pidx = (s * 4 + jj) * 2 + b;
        acc += g[pidx * C_ + c] * bf2f(mji[((size_t)pidx * C_ + c) * N_ + n]);
    }
    float inter = scale * acc + 4.f * bn_beta[c];
    msg[e] = intra_w[0] * eii[e] + inter_w[0] * inter;
}

// update: z/hhat reconstructed from split-K partials (+bias, activations)
__global__ void update_kernel(const float* __restrict__ zrp, const float* __restrict__ zrb,
                              const float* __restrict__ hhp, const float* __restrict__ ghb,
                              const float* __restrict__ h, float* __restrict__ out)
{
    const size_t ZP = (size_t)SB * C2 * N_;
    const size_t HP = (size_t)SB * C_ * N_;
    int e = blockIdx.x * blockDim.x + threadIdx.x;
    if (e >= SB * C_ * N_) return;
    int n = e % N_;
    int c = (e / N_) % C_;
    int img = e / (N_ * C_);
    size_t zi = ((size_t)img * C2 + c) * N_ + n;
    float z = 1.f / (1.f + __expf(-(zrp[zi] + zrp[ZP + zi] + zrb[c])));
    size_t hi = ((size_t)img * C_ + c) * N_ + n;
    float hh = tanhf(hhp[hi] + hhp[HP + hi] + ghb[c]);
    out[e] = (2.f - z) * h[e] + z * hh;
}

// ------------------------------------------------------------------- launcher
extern "C" void kernel_launch(void* const* d_in, const int* in_sizes, int n_in,
                              void* d_out, int out_size, void* d_ws, size_t ws_size,
                              hipStream_t stream)
{
    const float* x      = (const float*)d_in[0];
    const float* Wf_w   = (const float*)d_in[1];
    const float* Wf_b   = (const float*)d_in[2];
    const float* Wh_w   = (const float*)d_in[3];
    const float* Wh_b   = (const float*)d_in[4];
    const float* Wl_w   = (const float*)d_in[5];
    const float* Wl_b   = (const float*)d_in[6];
    const float* alpha  = (const float*)d_in[7];
    const float* Wc     = (const float*)d_in[8];
    const float* Wg_w   = (const float*)d_in[9];
    const float* Wg_b   = (const float*)d_in[10];
    const float* bng    = (const float*)d_in[11];
    const float* bnb    = (const float*)d_in[12];
    const float* zr_w   = (const float*)d_in[13];
    const float* zr_b   = (const float*)d_in[14];
    const float* gh_w   = (const float*)d_in[15];
    const float* gh_b   = (const float*)d_in[16];
    const float* intraw = (const float*)d_in[17];
    const float* interw = (const float*)d_in[18];
    float* outp = (float*)d_out;

    float* f = (float*)d_ws;
    const size_t SZ = (size_t)SB * C_ * N_;
    float* hbuf  = f; f += SZ;
    float* eii   = f; f += SZ;                       // msg written in-place
    float* zrp   = f; f += 2 * (size_t)SB * C2 * N_;
    float* hhp   = f; f += 2 * SZ;
    float* wsumb = f; f += (size_t)NPAIR * C_ * 9;
    float* gbuf  = f; f += (size_t)NPAIR * C_;
    unsigned short* us = (unsigned short*)f;
    unsigned short* mji16  = us; us += (size_t)NPAIR * C_ * N_;
    unsigned short* hT16   = us; us += SZ;
    unsigned short* hc16   = us; us += SZ;           // also reused as rhbT16
    unsigned short* msgT16 = us; us += SZ;
    unsigned short* ftT    = us; us += SZ;           // also reused as ytT
    unsigned short* htT    = us; us += SZ;
    unsigned short* lt16   = us; us += SZ;
    unsigned short* Wp3    = us; us += (size_t)384 * 1152;
    unsigned short* Wpzr   = us; us += (size_t)256 * 6400;
    unsigned short* Wph    = us; us += (size_t)128 * 6400;
    unsigned short* Wcb    = us; us += (size_t)128 * 128;

    unsigned short* ytT    = ftT;
    unsigned short* rhbT16 = hc16;

    const int NELEM = SB * C_ * N_;
    dim3 eb((NELEM + 255) / 256);

    pack3_kernel<<<(384 * 1152 + 255) / 256, 256, 0, stream>>>(Wf_w, Wh_w, Wl_w, Wp3);
    pack5_kernel<<<(256 * 6400 + 255) / 256, 256, 0, stream>>>(zr_w, Wpzr, 256);
    pack5_kernel<<<(128 * 6400 + 255) / 256, 256, 0, stream>>>(gh_w, Wph, 128);
    packWc_kernel<<<64, 256, 0, stream>>>(Wc, Wcb);

    const float* hcur = x;
    for (int it = 0; it < 3; ++it) {
        float* hout = (it == 2) ? outp : hbuf;
        float* msg = eii;

        tc_kernel<<<dim3(9, SB), 256, 0, stream>>>(hcur, nullptr, nullptr, hT16, hc16);
        conv_mfma<9, 1, 1, 0><<<dim3(3, 9, SB), 256, 0, stream>>>(
            hT16, hT16, Wp3, 384, Wf_b, Wh_b, Wl_b, nullptr, ftT, htT, lt16);
        attn_mfma<0><<<dim3(36, SB), 256, 0, stream>>>(ftT, htT, lt16, eii, nullptr, hcur, alpha);
        yt_mfma<<<dim3(36, SB), 256, 0, stream>>>(hT16, Wcb, ytT);
        attn_mfma<1><<<dim3(36, NPAIR), 256, 0, stream>>>(hT16, ytT, hc16, nullptr, mji16, nullptr, nullptr);
        wsum_kernel<<<dim3(NPAIR, C_), 64, 0, stream>>>(mji16, wsumb);
        g_kernel<<<NPAIR, 128, 0, stream>>>(wsumb, Wg_w, Wg_b, gbuf);
        msg_kernel<<<eb, 256, 0, stream>>>(eii, mji16, gbuf, bng, bnb, intraw, interw, msg);
        tc_kernel<<<dim3(9, SB), 256, 0, stream>>>(msg, nullptr, nullptr, msgT16, nullptr);
        conv_mfma<25, 2, 2, 1><<<dim3(4, 9, SB), 256, 0, stream>>>(
            msgT16, hT16, Wpzr, 256, nullptr, nullptr, nullptr, zrp, nullptr, nullptr, nullptr);
        tc_kernel<<<dim3(9, SB), 256, 0, stream>>>(hcur, zrp, zr_b, rhbT16, nullptr);
        conv_mfma<25, 2, 2, 1><<<dim3(2, 9, SB), 256, 0, stream>>>(
            msgT16, rhbT16, Wph, 128, nullptr, nullptr, nullptr, hhp, nullptr, nullptr, nullptr);
        update_kernel<<<eb, 256, 0, stream>>>(zrp, zr_b, hhp, gh_b, hcur, hout);
        hcur = hout;
    }
}

// Round 5
// 1198.962 us; speedup vs baseline: 1.6466x; 1.6466x over previous
//
#include <hip/hip_runtime.h>
#include <math.h>

#define S_  5
#define B_  2
#define C_  128
#define N_  576
#define SB  10
#define NPAIR 40
#define C2  256

typedef short v8s __attribute__((ext_vector_type(8)));
typedef float v4f __attribute__((ext_vector_type(4)));

#define GLOBAL_AS __attribute__((address_space(1)))
#define LDS_AS    __attribute__((address_space(3)))

__device__ __forceinline__ unsigned short f2bf(float f) {
    union { float f; unsigned u; } v; v.f = f;
    unsigned r = (v.u + 0x7FFF + ((v.u >> 16) & 1)) >> 16;
    return (unsigned short)r;
}
__device__ __forceinline__ float bf2f(unsigned short h) {
    union { unsigned u; float f; } v; v.u = ((unsigned)h) << 16;
    return v.f;
}

// ------------------------------------------------------------------ weight packs
__global__ void pack3_kernel(const float* __restrict__ wf, const float* __restrict__ wh,
                             const float* __restrict__ wl, unsigned short* __restrict__ Wp3)
{
    int idx = blockIdx.x * 256 + threadIdx.x;
    if (idx >= 384 * 1152) return;
    int co = idx / 1152, k = idx % 1152;
    int tap = k >> 7, ci = k & 127;
    const float* w = (co < 128) ? wf : (co < 256) ? wh : wl;
    int c = co & 127;
    Wp3[idx] = f2bf(w[((size_t)c * 128 + ci) * 9 + tap]);
}
__global__ void pack5_kernel(const float* __restrict__ w, unsigned short* __restrict__ Wp, int M)
{
    int idx = blockIdx.x * 256 + threadIdx.x;
    if (idx >= M * 6400) return;
    int co = idx / 6400, k = idx % 6400;
    int tap = k >> 8, ci = k & 255;
    Wp[idx] = f2bf(w[((size_t)co * 256 + ci) * 25 + tap]);
}
__global__ void packWc_kernel(const float* __restrict__ w, unsigned short* __restrict__ o)
{
    int idx = blockIdx.x * 256 + threadIdx.x;
    if (idx < 128 * 128) o[idx] = f2bf(w[idx]);
}

// ---------------------------------------------- transpose-cast: [c][px] f32 -> [px][c] bf16
__global__ __launch_bounds__(256) void tc_kernel(
    const float* __restrict__ src, const float* __restrict__ zrp,
    const float* __restrict__ zrb,
    unsigned short* __restrict__ dst, unsigned short* __restrict__ dst2)
{
    const size_t PLANE = (size_t)SB * C2 * N_;
    __shared__ float tile[128][65];
    int img = blockIdx.y, px0 = blockIdx.x * 64, t = threadIdx.x;
    #pragma unroll
    for (int i = 0; i < 32; ++i) {
        int e = i * 256 + t; int ci = e >> 6; int px = e & 63;
        float v = src[((size_t)img * 128 + ci) * 576 + px0 + px];
        if (zrp) {
            size_t zi = ((size_t)img * C2 + 128 + ci) * 576 + px0 + px;
            float a = zrp[zi] + zrp[PLANE + zi] + zrb[128 + ci];
            v *= 1.f / (1.f + __expf(-a));
        }
        tile[ci][px] = v;
        if (dst2) dst2[((size_t)img * 128 + ci) * 576 + px0 + px] = f2bf(v);
    }
    __syncthreads();
    #pragma unroll
    for (int i = 0; i < 32; ++i) {
        int e = i * 256 + t; int px = e >> 7; int ci = e & 127;
        dst[((size_t)img * 576 + px0 + px) * 128 + ci] = f2bf(tile[ci][px]);
    }
}

// ------------------------------------------------------ MFMA implicit-GEMM conv v3
// block tile: 128co x 64px, 4 waves (wave = 64co x 32px)
// B window: global_load_lds 16B (zero VGPR staging), double-buffered LDS,
//           XOR swizzle applied via source permutation (slot->gr), boundary pre-zeroed
// A weights: direct-global with depth-DEPTH register ring (DEPTH | TAPS)
template<int TAPS, int R, int SPLITK, int MODE>
__global__ __launch_bounds__(256, 2) void conv_mfma(
    const unsigned short* __restrict__ srcA, const unsigned short* __restrict__ srcB,
    const unsigned short* __restrict__ Wp, int COUT,
    const float* __restrict__ b0, const float* __restrict__ b1, const float* __restrict__ b2,
    float* __restrict__ po,
    unsigned short* __restrict__ t0, unsigned short* __restrict__ t1,
    unsigned short* __restrict__ t2)
{
    constexpr int KD    = 2 * R + 1;
    constexpr int WR    = 4 + 2 * R;
    constexpr int WC    = 24 + 2 * R;
    constexpr int NPOS  = WR * WC;
    constexpr int NSLOT = NPOS * 4;            // 16B slots per chunk image
    constexpr int CIN   = (SPLITK == 2) ? 256 : 128;
    constexpr int KTOT  = TAPS * CIN;
    constexpr int NCH   = 4;                   // ci chunks of 32 per K-part
    constexpr int DEPTH = (TAPS == 25) ? 5 : 3;
    constexpr int ROUNDS = (NSLOT + 255) / 256;
    __shared__ __align__(16) unsigned short Xs[2][NPOS * 32];

    int f   = blockIdx.x;
    int kk  = (SPLITK == 2) ? (f & 1) : 0;
    int cgb = (SPLITK == 2) ? (f >> 1) : f;
    int pxb = blockIdx.y;
    int img = blockIdx.z;
    int t = threadIdx.x;
    int wave = t >> 6, lane = t & 63;
    int quad = lane >> 4, l15 = lane & 15;
    int cgw = wave & 1, pgw = wave >> 1;
    int px0w = pxb * 64 + pgw * 32;
    int r0 = (pxb * 64) / 24;

    const unsigned short* src = (SPLITK == 2 && kk == 1) ? srcB : srcA;
    const unsigned short* srcI = src + (size_t)img * 576 * 128;

    int posBase[2], pxs[2];
    #pragma unroll
    for (int s = 0; s < 2; ++s) {
        int px = px0w + s * 16 + l15;
        pxs[s] = px;
        int pr = px / 24, pc = px % 24;
        posBase[s] = (pr - r0 + R) * WC + pc + R;
    }

    const unsigned short* wRow = Wp + (size_t)(cgb * 128 + cgw * 64 + l15) * KTOT
                                 + (SPLITK == 2 ? kk * 128 : 0) + quad * 8;

    // per-lane staging source geometry (slot -> swizzled gr -> global addr)
    int sIdxInWave = lane;            // idx within a 256-slot round = wave*64 + lane
    // zero both buffers (boundary slots stay zero forever)
    {
        v8s zv;
        #pragma unroll
        for (int j = 0; j < 8; ++j) zv[j] = 0;
        unsigned short* xsf = &Xs[0][0];
        for (int i = t; i < NPOS * 8; i += 256) *(v8s*)&xsf[(size_t)i * 8] = zv;
    }
    __syncthreads();

    auto stage = [&](int ch, int buf) {
        const unsigned short* sp = srcI + ch * 32;
        char* lbase = (char*)&Xs[buf][0];
        #pragma unroll
        for (int rr = 0; rr < ROUNDS; ++rr) {
            int idx0 = rr * 256 + wave * 64;
            if (idx0 < NSLOT) {
                int idx = idx0 + sIdxInWave;
                int pos = idx >> 2, slot = idx & 3;
                int gr = slot ^ ((pos >> 1) & 3);
                int wr = pos / WC, wc = pos % WC;
                int grow = r0 - R + wr, gcol = wc - R;
                bool ok = (idx < NSLOT) && grow >= 0 && grow < 24 && gcol >= 0 && gcol < 24;
                if (ok) {
                    __builtin_amdgcn_global_load_lds(
                        (const GLOBAL_AS void*)(sp + (size_t)(grow * 24 + gcol) * 128 + gr * 8),
                        (LDS_AS void*)(lbase + (size_t)idx0 * 16),
                        16, 0, 0);
                }
            }
        }
    };

    v8s abuf[DEPTH][4];
    auto loadA = [&](int ch, int tap, int slot) {
        const unsigned short* p = wRow + ch * 32 + tap * CIN;
        #pragma unroll
        for (int c = 0; c < 4; ++c)
            abuf[slot][c] = *(const v8s*)(p + (size_t)c * 16 * KTOT);
    };

    v4f acc[4][2];
    #pragma unroll
    for (int c = 0; c < 4; ++c)
        #pragma unroll
        for (int s = 0; s < 2; ++s)
            #pragma unroll
            for (int r = 0; r < 4; ++r) acc[c][s][r] = 0.f;

    stage(0, 0);
    #pragma unroll
    for (int d = 0; d < DEPTH; ++d) loadA(0, d, d);
    __syncthreads();   // drains staging vmcnt before reads

    #pragma unroll 1
    for (int ch = 0; ch < NCH; ++ch) {
        if (ch + 1 < NCH) stage(ch + 1, (ch + 1) & 1);
        const unsigned short* XsBuf = &Xs[ch & 1][0];
        const int chn = (ch + 1 < NCH) ? ch + 1 : ch;   // clamped prefetch target

        #pragma unroll
        for (int tap = 0; tap < TAPS; ++tap) {
            const int slot = tap % DEPTH;
            const int dy = tap / KD - R, dx = tap % KD - R;
            const int doff = dy * WC + dx;
            v8s bfr[2];
            #pragma unroll
            for (int s = 0; s < 2; ++s) {
                int pos = posBase[s] + doff;
                bfr[s] = *(const v8s*)&XsBuf[pos * 32 + ((quad ^ ((pos >> 1) & 3)) << 3)];
            }
            #pragma unroll
            for (int c = 0; c < 4; ++c)
                #pragma unroll
                for (int s = 0; s < 2; ++s)
                    acc[c][s] = __builtin_amdgcn_mfma_f32_16x16x32_bf16(abuf[slot][c], bfr[s], acc[c][s], 0, 0, 0);
            // ring prefetch (slot just consumed)
            if (tap + DEPTH < TAPS) loadA(ch, tap + DEPTH, slot);
            else                    loadA(chn, tap + DEPTH - TAPS, slot);
        }
        __syncthreads();   // staging of ch+1 drained; all reads of this buf done
    }

    if (MODE == 1) {
        float* out = po + (size_t)kk * ((size_t)SB * COUT * 576)
                   + ((size_t)img * COUT + cgb * 128) * 576;
        #pragma unroll
        for (int c = 0; c < 4; ++c)
            #pragma unroll
            for (int s = 0; s < 2; ++s)
                #pragma unroll
                for (int r = 0; r < 4; ++r) {
                    int col = cgw * 64 + c * 16 + quad * 4 + r;
                    out[(size_t)col * 576 + pxs[s]] = acc[c][s][r];
                }
    } else {
        const float* bp = (cgb == 0) ? b0 : (cgb == 1) ? b1 : b2;
        #pragma unroll
        for (int c = 0; c < 4; ++c)
            #pragma unroll
            for (int s = 0; s < 2; ++s)
                #pragma unroll
                for (int r = 0; r < 4; ++r) {
                    int col = cgw * 64 + c * 16 + quad * 4 + r;
                    float v = acc[c][s][r] + bp[col];
                    if (cgb == 0)      t0[((size_t)img * 576 + pxs[s]) * 128 + col] = f2bf(v);
                    else if (cgb == 1) t1[((size_t)img * 576 + pxs[s]) * 128 + col] = f2bf(v);
                    else               t2[((size_t)img * 128 + col) * 576 + pxs[s]] = f2bf(v);
                }
    }
}

// ---------------------------------------------------------------- yt (MFMA)
__global__ __launch_bounds__(256) void yt_mfma(
    const unsigned short* __restrict__ hT, const unsigned short* __restrict__ Wcb,
    unsigned short* __restrict__ ytT)
{
    int t = threadIdx.x, wave = t >> 6, lane = t & 63;
    int q = lane >> 4, l15 = lane & 15;
    int n0 = blockIdx.x * 16, img = blockIdx.y;
    v4f acc[2];
    #pragma unroll
    for (int ct = 0; ct < 2; ++ct)
        #pragma unroll
        for (int r = 0; r < 4; ++r) acc[ct][r] = 0.f;
    #pragma unroll
    for (int kk = 0; kk < 4; ++kk) {
        v8s b = *(const v8s*)(hT + ((size_t)img * 576 + n0 + l15) * 128 + kk * 32 + q * 8);
        #pragma unroll
        for (int ct = 0; ct < 2; ++ct) {
            v8s a = *(const v8s*)(Wcb + (size_t)((wave * 2 + ct) * 16 + l15) * 128 + kk * 32 + q * 8);
            acc[ct] = __builtin_amdgcn_mfma_f32_16x16x32_bf16(a, b, acc[ct], 0, 0, 0);
        }
    }
    #pragma unroll
    for (int ct = 0; ct < 2; ++ct) {
        unsigned short* op = ytT + ((size_t)img * 576 + n0 + l15) * 128 + (wave * 2 + ct) * 16 + q * 4;
        #pragma unroll
        for (int r = 0; r < 4; ++r) op[r] = f2bf(acc[ct][r]);
    }
}

// ---------------------------------------------------- MFMA flash attention
template<int MODE>
__global__ __launch_bounds__(256) void attn_mfma(
    const unsigned short* __restrict__ QT, const unsigned short* __restrict__ KT,
    const unsigned short* __restrict__ Vc, float* __restrict__ Of,
    unsigned short* __restrict__ Oh, const float* __restrict__ addsrc,
    const float* __restrict__ alpha)
{
    __shared__ __align__(16) unsigned short P[16 * 576];
    __shared__ float redmx[4][16];
    __shared__ float redsm[4][16];
    int t = threadIdx.x;
    int wave = t >> 6, lane = t & 63;
    int q = lane >> 4, l15 = lane & 15;
    int n0 = blockIdx.x * 16;
    int p = blockIdx.y;
    int qimg, kimg;
    if (MODE == 0) { qimg = p; kimg = p; }
    else {
        int b = p & 1; int ij = p >> 1; int i = ij >> 2; int jj = ij & 3;
        int j = jj + (jj >= i ? 1 : 0);
        qimg = i * 2 + b; kimg = j * 2 + b;
    }
    const unsigned short* Qp = QT + ((size_t)qimg * 576 + n0) * 128;
    const unsigned short* Kp = KT + (size_t)kimg * 576 * 128;
    const unsigned short* Vp = Vc + (size_t)kimg * 128 * 576;

    v8s aq[4];
    #pragma unroll
    for (int kk = 0; kk < 4; ++kk)
        aq[kk] = *(const v8s*)(Qp + (size_t)l15 * 128 + kk * 32 + q * 8);

    v4f S[9];
    #pragma unroll
    for (int i = 0; i < 9; ++i)
        #pragma unroll
        for (int r = 0; r < 4; ++r) S[i][r] = 0.f;

    #pragma unroll
    for (int i = 0; i < 9; ++i) {
        int m0 = (wave * 9 + i) * 16;
        #pragma unroll
        for (int kk = 0; kk < 4; ++kk) {
            v8s b = *(const v8s*)(Kp + ((size_t)(m0 + l15)) * 128 + kk * 32 + q * 8);
            S[i] = __builtin_amdgcn_mfma_f32_16x16x32_bf16(aq[kk], b, S[i], 0, 0, 0);
        }
    }

    float mx[4];
    #pragma unroll
    for (int r = 0; r < 4; ++r) {
        float m = S[0][r];
        #pragma unroll
        for (int i = 1; i < 9; ++i) m = fmaxf(m, S[i][r]);
        #pragma unroll
        for (int off = 1; off < 16; off <<= 1) m = fmaxf(m, __shfl_xor(m, off));
        mx[r] = m;
    }
    if (l15 == 0) {
        #pragma unroll
        for (int r = 0; r < 4; ++r) redmx[wave][q * 4 + r] = mx[r];
    }
    __syncthreads();
    float sum[4];
    #pragma unroll
    for (int r = 0; r < 4; ++r) {
        float g = fmaxf(fmaxf(redmx[0][q * 4 + r], redmx[1][q * 4 + r]),
                        fmaxf(redmx[2][q * 4 + r], redmx[3][q * 4 + r]));
        float s = 0.f;
        #pragma unroll
        for (int i = 0; i < 9; ++i) { float e = __expf(S[i][r] - g); S[i][r] = e; s += e; }
        #pragma unroll
        for (int off = 1; off < 16; off <<= 1) s += __shfl_xor(s, off);
        sum[r] = s;
    }
    if (l15 == 0) {
        #pragma unroll
        for (int r = 0; r < 4; ++r) redsm[wave][q * 4 + r] = sum[r];
    }
    #pragma unroll
    for (int i = 0; i < 9; ++i) {
        int m = (wave * 9 + i) * 16 + l15;
        int cm = m >> 3, mo = m & 7;
        #pragma unroll
        for (int r = 0; r < 4; ++r) {
            int n = q * 4 + r;
            P[n * 576 + ((cm ^ (n & 7)) << 3) + mo] = f2bf(S[i][r]);
        }
    }
    __syncthreads();
    float inv[4];
    #pragma unroll
    for (int r = 0; r < 4; ++r)
        inv[r] = 1.f / (redsm[0][q * 4 + r] + redsm[1][q * 4 + r] +
                        redsm[2][q * 4 + r] + redsm[3][q * 4 + r]);

    v4f o[2];
    #pragma unroll
    for (int ct = 0; ct < 2; ++ct)
        #pragma unroll
        for (int r = 0; r < 4; ++r) o[ct][r] = 0.f;

    for (int s = 0; s < 18; ++s) {
        int cm = s * 4 + q;
        v8s a = *(const v8s*)&P[l15 * 576 + ((cm ^ (l15 & 7)) << 3)];
        #pragma unroll
        for (int ct = 0; ct < 2; ++ct) {
            int c = (wave * 2 + ct) * 16 + l15;
            v8s b = *(const v8s*)(Vp + (size_t)c * 576 + s * 32 + q * 8);
            o[ct] = __builtin_amdgcn_mfma_f32_16x16x32_bf16(a, b, o[ct], 0, 0, 0);
        }
    }

    #pragma unroll
    for (int ct = 0; ct < 2; ++ct) {
        int c = (wave * 2 + ct) * 16 + l15;
        size_t base = ((size_t)p * 128 + c) * 576 + n0 + q * 4;
        if (MODE == 0) {
            float al = alpha[0];
            #pragma unroll
            for (int r = 0; r < 4; ++r)
                Of[base + r] = al * o[ct][r] * inv[r] + addsrc[base + r];
        } else {
            #pragma unroll
            for (int r = 0; r < 4; ++r)
                Oh[base + r] = f2bf(o[ct][r] * inv[r]);
        }
    }
}

// ------------------------------------- window sums for analytic gate-conv mean
__global__ __launch_bounds__(64) void wsum_kernel(
    const unsigned short* __restrict__ mji, float* __restrict__ wsum)
{
    int pair = blockIdx.x, ci = blockIdx.y, lane = threadIdx.x;
    const unsigned short* p = mji + ((size_t)pair * C_ + ci) * N_;
    float T=0, R0=0, R23=0, Cl=0, Cr=0, c00=0, c0w=0, ch0=0, chw=0;
    for (int i = lane; i < N_; i += 64) {
        float v = bf2f(p[i]);
        int r = i / 24, cc = i % 24;
        T += v;
        if (r == 0)  R0  += v;
        if (r == 23) R23 += v;
        if (cc == 0)  Cl += v;
        if (cc == 23) Cr += v;
        if (i == 0)   c00 = v;
        if (i == 23)  c0w = v;
        if (i == 552) ch0 = v;
        if (i == 575) chw = v;
    }
    #pragma unroll
    for (int off = 32; off > 0; off >>= 1) {
        T  += __shfl_xor(T, off);  R0 += __shfl_xor(R0, off);  R23 += __shfl_xor(R23, off);
        Cl += __shfl_xor(Cl, off); Cr += __shfl_xor(Cr, off);
        c00 += __shfl_xor(c00, off); c0w += __shfl_xor(c0w, off);
        ch0 += __shfl_xor(ch0, off); chw += __shfl_xor(chw, off);
    }
    if (lane == 0) {
        float rowsub[3] = {R23, 0.f, R0};
        float colsub[3] = {Cr,  0.f, Cl};
        float corner[9] = {chw, 0.f, ch0,  0.f, 0.f, 0.f,  c0w, 0.f, c00};
        float* o = wsum + ((size_t)pair * C_ + ci) * 9;
        #pragma unroll
        for (int ky = 0; ky < 3; ++ky)
            #pragma unroll
            for (int kx = 0; kx < 3; ++kx)
                o[ky * 3 + kx] = T - rowsub[ky] - colsub[kx] + corner[ky * 3 + kx];
    }
}

__global__ __launch_bounds__(128) void g_kernel(
    const float* __restrict__ wsum, const float* __restrict__ Wg,
    const float* __restrict__ Wgb, float* __restrict__ g)
{
    __shared__ float sw[C_ * 9];
    int pair = blockIdx.x; int co = threadIdx.x;
    for (int i = co; i < C_ * 9; i += 128) sw[i] = wsum[(size_t)pair * C_ * 9 + i];
    __syncthreads();
    const float* w = Wg + (size_t)co * C_ * 9;
    float acc = 0.f;
    for (int i = 0; i < C_ * 9; ++i) acc += w[i] * sw[i];
    float m = acc * (1.f / 576.f) + Wgb[co];
    g[pair * C_ + co] = 1.f / (1.f + __expf(-m));
}

__global__ void msg_kernel(
    const float* __restrict__ eii, const unsigned short* __restrict__ mji,
    const float* __restrict__ g, const float* __restrict__ bn_gamma,
    const float* __restrict__ bn_beta, const float* __restrict__ intra_w,
    const float* __restrict__ inter_w, float* __restrict__ msg)
{
    int e = blockIdx.x * blockDim.x + threadIdx.x;
    if (e >= SB * C_ * N_) return;
    int n = e % N_;
    int c = (e / N_) % C_;
    int img = e / (N_ * C_);
    int s = img >> 1, b = img & 1;
    float scale = bn_gamma[c] * rsqrtf(1.f + 1e-5f);
    float acc = 0.f;
    #pragma unroll
    for (int jj = 0; jj < 4; ++jj) {
        int pidx = (s * 4 + jj) * 2 + b;
        acc += g[pidx * C_ + c] * bf2f(mji[((size_t)pidx * C_ + c) * N_ + n]);
    }
    float inter = scale * acc + 4.f * bn_beta[c];
    msg[e] = intra_w[0] * eii[e] + inter_w[0] * inter;
}

// update: z/hhat reconstructed from split-K partials (+bias, activations)
__global__ void update_kernel(const float* __restrict__ zrp, const float* __restrict__ zrb,
                              const float* __restrict__ hhp, const float* __restrict__ ghb,
                              const float* __restrict__ h, float* __restrict__ out)
{
    const size_t ZP = (size_t)SB * C2 * N_;
    const size_t HP = (size_t)SB * C_ * N_;
    int e = blockIdx.x * blockDim.x + threadIdx.x;
    if (e >= SB * C_ * N_) return;
    int n = e % N_;
    int c = (e / N_) % C_;
    int img = e / (N_ * C_);
    size_t zi = ((size_t)img * C2 + c) * N_ + n;
    float z = 1.f / (1.f + __expf(-(zrp[zi] + zrp[ZP + zi] + zrb[c])));
    size_t hi = ((size_t)img * C_ + c) * N_ + n;
    float hh = tanhf(hhp[hi] + hhp[HP + hi] + ghb[c]);
    out[e] = (2.f - z) * h[e] + z * hh;
}

// ------------------------------------------------------------------- launcher
extern "C" void kernel_launch(void* const* d_in, const int* in_sizes, int n_in,
                              void* d_out, int out_size, void* d_ws, size_t ws_size,
                              hipStream_t stream)
{
    const float* x      = (const float*)d_in[0];
    const float* Wf_w   = (const float*)d_in[1];
    const float* Wf_b   = (const float*)d_in[2];
    const float* Wh_w   = (const float*)d_in[3];
    const float* Wh_b   = (const float*)d_in[4];
    const float* Wl_w   = (const float*)d_in[5];
    const float* Wl_b   = (const float*)d_in[6];
    const float* alpha  = (const float*)d_in[7];
    const float* Wc     = (const float*)d_in[8];
    const float* Wg_w   = (const float*)d_in[9];
    const float* Wg_b   = (const float*)d_in[10];
    const float* bng    = (const float*)d_in[11];
    const float* bnb    = (const float*)d_in[12];
    const float* zr_w   = (const float*)d_in[13];
    const float* zr_b   = (const float*)d_in[14];
    const float* gh_w   = (const float*)d_in[15];
    const float* gh_b   = (const float*)d_in[16];
    const float* intraw = (const float*)d_in[17];
    const float* interw = (const float*)d_in[18];
    float* outp = (float*)d_out;

    float* f = (float*)d_ws;
    const size_t SZ = (size_t)SB * C_ * N_;
    float* hbuf  = f; f += SZ;
    float* eii   = f; f += SZ;                       // msg written in-place
    float* zrp   = f; f += 2 * (size_t)SB * C2 * N_;
    float* hhp   = f; f += 2 * SZ;
    float* wsumb = f; f += (size_t)NPAIR * C_ * 9;
    float* gbuf  = f; f += (size_t)NPAIR * C_;
    unsigned short* us = (unsigned short*)f;
    unsigned short* mji16  = us; us += (size_t)NPAIR * C_ * N_;
    unsigned short* hT16   = us; us += SZ;
    unsigned short* hc16   = us; us += SZ;           // also reused as rhbT16
    unsigned short* msgT16 = us; us += SZ;
    unsigned short* ftT    = us; us += SZ;           // also reused as ytT
    unsigned short* htT    = us; us += SZ;
    unsigned short* lt16   = us; us += SZ;
    unsigned short* Wp3    = us; us += (size_t)384 * 1152;
    unsigned short* Wpzr   = us; us += (size_t)256 * 6400;
    unsigned short* Wph    = us; us += (size_t)128 * 6400;
    unsigned short* Wcb    = us; us += (size_t)128 * 128;

    unsigned short* ytT    = ftT;
    unsigned short* rhbT16 = hc16;

    const int NELEM = SB * C_ * N_;
    dim3 eb((NELEM + 255) / 256);

    pack3_kernel<<<(384 * 1152 + 255) / 256, 256, 0, stream>>>(Wf_w, Wh_w, Wl_w, Wp3);
    pack5_kernel<<<(256 * 6400 + 255) / 256, 256, 0, stream>>>(zr_w, Wpzr, 256);
    pack5_kernel<<<(128 * 6400 + 255) / 256, 256, 0, stream>>>(gh_w, Wph, 128);
    packWc_kernel<<<64, 256, 0, stream>>>(Wc, Wcb);

    const float* hcur = x;
    for (int it = 0; it < 3; ++it) {
        float* hout = (it == 2) ? outp : hbuf;
        float* msg = eii;

        tc_kernel<<<dim3(9, SB), 256, 0, stream>>>(hcur, nullptr, nullptr, hT16, hc16);
        conv_mfma<9, 1, 1, 0><<<dim3(3, 9, SB), 256, 0, stream>>>(
            hT16, hT16, Wp3, 384, Wf_b, Wh_b, Wl_b, nullptr, ftT, htT, lt16);
        attn_mfma<0><<<dim3(36, SB), 256, 0, stream>>>(ftT, htT, lt16, eii, nullptr, hcur, alpha);
        yt_mfma<<<dim3(36, SB), 256, 0, stream>>>(hT16, Wcb, ytT);
        attn_mfma<1><<<dim3(36, NPAIR), 256, 0, stream>>>(hT16, ytT, hc16, nullptr, mji16, nullptr, nullptr);
        wsum_kernel<<<dim3(NPAIR, C_), 64, 0, stream>>>(mji16, wsumb);
        g_kernel<<<NPAIR, 128, 0, stream>>>(wsumb, Wg_w, Wg_b, gbuf);
        msg_kernel<<<eb, 256, 0, stream>>>(eii, mji16, gbuf, bng, bnb, intraw, interw, msg);
        tc_kernel<<<dim3(9, SB), 256, 0, stream>>>(msg, nullptr, nullptr, msgT16, nullptr);
        conv_mfma<25, 2, 2, 1><<<dim3(4, 9, SB), 256, 0, stream>>>(
            msgT16, hT16, Wpzr, 256, nullptr, nullptr, nullptr, zrp, nullptr, nullptr, nullptr);
        tc_kernel<<<dim3(9, SB), 256, 0, stream>>>(hcur, zrp, zr_b, rhbT16, nullptr);
        conv_mfma<25, 2, 2, 1><<<dim3(2, 9, SB), 256, 0, stream>>>(
            msgT16, rhbT16, Wph, 128, nullptr, nullptr, nullptr, hhp, nullptr, nullptr, nullptr);
        update_kernel<<<eb, 256, 0, stream>>>(zrp, zr_b, hhp, gh_b, hcur, hout);
        hcur = hout;
    }
}